// Round 3
// baseline (665.427 us; speedup 1.0000x reference)
//
#include <hip/hip_runtime.h>

#define N_NODES 50000
#define N_EDGES 800000

#define SCAN_CHUNK 256
#define SCAN_BLOCKS ((N_NODES + SCAN_CHUNK - 1) / SCAN_CHUNK) // 196

static inline size_t alignUp(size_t x, size_t a) { return (x + a - 1) & ~(a - 1); }

// ---------------- CSR build ----------------

__global__ void k_zero_i32(int* __restrict__ p, int n) {
    int i = blockIdx.x * 256 + threadIdx.x;
    if (i < n) p[i] = 0;
}

__global__ void k_count(const int* __restrict__ row, int* __restrict__ count) {
    int e = blockIdx.x * 256 + threadIdx.x;
    if (e < N_EDGES) atomicAdd(&count[row[e]], 1);
}

__global__ void k_blocksum(const int* __restrict__ count, int* __restrict__ bsum) {
    __shared__ int s[256];
    int t = threadIdx.x;
    int i = blockIdx.x * 256 + t;
    int v = (i < N_NODES) ? count[i] : 0;
    s[t] = v;
    __syncthreads();
    for (int off = 128; off > 0; off >>= 1) {
        if (t < off) s[t] += s[t + off];
        __syncthreads();
    }
    if (t == 0) bsum[blockIdx.x] = s[0];
}

__global__ void k_scan_bsum(int* __restrict__ bsum) {
    __shared__ int s[256];
    int t = threadIdx.x;
    int v = (t < SCAN_BLOCKS) ? bsum[t] : 0;
    s[t] = v;
    __syncthreads();
    for (int off = 1; off < 256; off <<= 1) {
        int add = (t >= off) ? s[t - off] : 0;
        __syncthreads();
        s[t] += add;
        __syncthreads();
    }
    if (t < SCAN_BLOCKS) bsum[t] = s[t] - v; // exclusive
}

__global__ void k_scan_final(const int* __restrict__ count, const int* __restrict__ bsum,
                             int* __restrict__ offsets, int* __restrict__ cursor,
                             float* __restrict__ dinv) {
    __shared__ int s[256];
    int t = threadIdx.x;
    int i = blockIdx.x * 256 + t;
    int v = (i < N_NODES) ? count[i] : 0;
    s[t] = v;
    __syncthreads();
    for (int off = 1; off < 256; off <<= 1) {
        int add = (t >= off) ? s[t - off] : 0;
        __syncthreads();
        s[t] += add;
        __syncthreads();
    }
    if (i < N_NODES) {
        int excl = s[t] - v + bsum[blockIdx.x];
        offsets[i] = excl;
        cursor[i]  = excl;
        dinv[i]    = rsqrtf((float)(v + 1)); // +1 self-loop; always > 0
    }
}

__global__ void k_scatter(const int* __restrict__ row, const int* __restrict__ col,
                          int* __restrict__ cursor, int* __restrict__ csr_col) {
    int e = blockIdx.x * 256 + threadIdx.x;
    if (e < N_EDGES) {
        int r = row[e];
        int pos = atomicAdd(&cursor[r], 1);
        csr_col[pos] = col[e];
    }
}

// ---------------- prescale: o[i,:] = dinv[i] * f[i,:]  (F=64, float4 grain) ----

__global__ void k_prescale64(const float* __restrict__ f, const float* __restrict__ dinv,
                             float* __restrict__ o) {
    int i = blockIdx.x * 256 + threadIdx.x; // float4 index
    if (i < N_NODES * 16) {
        int node = i >> 4;
        float d = dinv[node];
        float4 v = reinterpret_cast<const float4*>(f)[i];
        reinterpret_cast<float4*>(o)[i] = make_float4(v.x * d, v.y * d, v.z * d, v.w * d);
    }
}

// ---------------- Aggregation over PRE-SCALED rows ----------------
// out[i] = dinv_i * ( h'[i] + sum_c h'[c] ) (+bias), h' = dinv .* h
// One node per WAVE (zero inter-node divergence). Predicated full-width
// batches; csr_col is padded by 16 zeroed entries so over-read is safe.

// F=128: 64 lanes x float2 = one row; 8 edges per batch.
template <bool BIAS>
__global__ __launch_bounds__(256) void k_agg128(const float* __restrict__ hs, float* __restrict__ out,
        const int* __restrict__ csr_col, const int* __restrict__ offsets,
        const int* __restrict__ count, const float* __restrict__ dinv,
        const float* __restrict__ bias) {
    int lane = threadIdx.x & 63;
    int node = blockIdx.x * 4 + (threadIdx.x >> 6);
    const float2* h2 = reinterpret_cast<const float2*>(hs);

    float ax[8], ay[8];
#pragma unroll
    for (int u = 0; u < 8; u++) { ax[u] = 0.f; ay[u] = 0.f; }

    int n = count[node];
    const int* cp = csr_col + offsets[node];

    int e = 0;
    for (; e + 8 <= n; e += 8) {
        int c[8];
#pragma unroll
        for (int u = 0; u < 8; u++) c[u] = cp[e + u];
#pragma unroll
        for (int u = 0; u < 8; u++) {
            float2 v = h2[(size_t)c[u] * 64 + lane];
            ax[u] += v.x; ay[u] += v.y;
        }
    }
    if (e < n) { // one predicated batch covers rem 1..7
        int c[8];
#pragma unroll
        for (int u = 0; u < 8; u++) c[u] = cp[e + u]; // padded, safe
#pragma unroll
        for (int u = 0; u < 8; u++) {
            float2 v = h2[(size_t)c[u] * 64 + lane];
            if (e + u < n) { ax[u] += v.x; ay[u] += v.y; }
        }
    }

    float sx = 0.f, sy = 0.f;
#pragma unroll
    for (int u = 0; u < 8; u++) { sx += ax[u]; sy += ay[u]; }
    float2 self = h2[(size_t)node * 64 + lane];
    float d = dinv[node];
    float ox = (sx + self.x) * d, oy = (sy + self.y) * d;
    if (BIAS) { ox += bias[2 * lane]; oy += bias[2 * lane + 1]; }
    reinterpret_cast<float2*>(out)[(size_t)node * 64 + lane] = make_float2(ox, oy);
}

// F=64: 32 lanes x float2 = one row; each load slot covers TWO edges
// (lane half 0 -> edge e+2u, half 1 -> edge e+2u+1): 16 edges per batch.
template <bool BIAS>
__global__ __launch_bounds__(256) void k_agg64(const float* __restrict__ hs, float* __restrict__ out,
        const int* __restrict__ csr_col, const int* __restrict__ offsets,
        const int* __restrict__ count, const float* __restrict__ dinv,
        const float* __restrict__ bias) {
    int lane = threadIdx.x & 63;
    int node = blockIdx.x * 4 + (threadIdx.x >> 6);
    int half = lane >> 5;
    int f2 = lane & 31;
    const float2* h2 = reinterpret_cast<const float2*>(hs);

    float ax[8], ay[8];
#pragma unroll
    for (int u = 0; u < 8; u++) { ax[u] = 0.f; ay[u] = 0.f; }

    int n = count[node];
    const int* cp = csr_col + offsets[node];

    int e = 0;
    for (; e + 16 <= n; e += 16) {
        int c[8];
#pragma unroll
        for (int u = 0; u < 8; u++) c[u] = cp[e + 2 * u + half];
#pragma unroll
        for (int u = 0; u < 8; u++) {
            float2 v = h2[(size_t)c[u] * 32 + f2];
            ax[u] += v.x; ay[u] += v.y;
        }
    }
    if (e < n) { // one predicated batch covers rem 1..15
#pragma unroll
        for (int u = 0; u < 8; u++) {
            int eid = e + 2 * u + half;
            int c = cp[eid]; // padded, safe
            float2 v = h2[(size_t)c * 32 + f2];
            if (eid < n) { ax[u] += v.x; ay[u] += v.y; }
        }
    }

    float sx = 0.f, sy = 0.f;
#pragma unroll
    for (int u = 0; u < 8; u++) { sx += ax[u]; sy += ay[u]; }
    sx += __shfl_xor(sx, 32);
    sy += __shfl_xor(sy, 32);
    if (half == 0) {
        float2 self = h2[(size_t)node * 32 + f2];
        float d = dinv[node];
        float ox = (sx + self.x) * d, oy = (sy + self.y) * d;
        if (BIAS) { ox += bias[2 * f2]; oy += bias[2 * f2 + 1]; }
        reinterpret_cast<float2*>(out)[(size_t)node * 32 + f2] = make_float2(ox, oy);
    }
}

// ---------------- fp32 GEMM: 64x64 block, BK=64, 4x4 micro-tile ----------------
// out[r,c] = post( x[r,:] @ W[:,c] ), post = (+bias) -> relu -> (*dinv[r])
// xt transposed [k][r] with XOR swizzle r^(k&~3): 2-way banks on store & read (free).

template <int K, int NOUT, bool RELU, bool BIAS, bool SCALE>
__global__ __launch_bounds__(256) void k_gemm(const float* __restrict__ x,
        const float* __restrict__ W, const float* __restrict__ bias,
        const float* __restrict__ dinv, float* __restrict__ out, int nrows) {
    constexpr int BM = 64, BN = 64, BK = 64;
    constexpr int NCB = NOUT / BN; // column blocks: 1 or 2
    __shared__ float xt[BK * BM]; // 16 KB, transposed+swizzled
    __shared__ float wt[BK * BN]; // 16 KB

    int tid = threadIdx.x;
    int row0 = (blockIdx.x / NCB) * BM;
    int col0 = (blockIdx.x % NCB) * BN;
    int rg = tid & 15;  // rows rg*4..+3
    int cg = tid >> 4;  // cols cg*4..+3

    float acc[4][4] = {};

    for (int kk = 0; kk < K; kk += BK) {
        if (kk) __syncthreads();
        // x tile: 64 rows x 64 k, coalesced float4, swizzled transpose store
#pragma unroll
        for (int t = 0; t < 4; ++t) {
            int idx = tid + t * 256;
            int r = idx >> 4;
            int kc = (idx & 15) * 4;
            float4 v = make_float4(0.f, 0.f, 0.f, 0.f);
            int gr = row0 + r;
            if (gr < nrows) v = *reinterpret_cast<const float4*>(&x[(size_t)gr * K + kk + kc]);
            int rc = r ^ kc;
            xt[(kc + 0) * BM + rc] = v.x;
            xt[(kc + 1) * BM + rc] = v.y;
            xt[(kc + 2) * BM + rc] = v.z;
            xt[(kc + 3) * BM + rc] = v.w;
        }
        // W tile: 64 k x 64 n
#pragma unroll
        for (int t = 0; t < 4; ++t) {
            int idx = tid + t * 256;
            int k = idx >> 4;
            int c = (idx & 15) * 4;
            *reinterpret_cast<float4*>(&wt[k * BN + c]) =
                *reinterpret_cast<const float4*>(&W[(size_t)(kk + k) * NOUT + col0 + c]);
        }
        __syncthreads();

#pragma unroll
        for (int k = 0; k < BK; ++k) {
            float4 xv = *reinterpret_cast<const float4*>(&xt[k * BM + ((rg * 4) ^ (k & ~3))]);
            float4 wv = *reinterpret_cast<const float4*>(&wt[k * BN + cg * 4]);
            float xr[4] = {xv.x, xv.y, xv.z, xv.w};
            float wr[4] = {wv.x, wv.y, wv.z, wv.w};
#pragma unroll
            for (int a = 0; a < 4; a++)
#pragma unroll
                for (int b = 0; b < 4; b++) acc[a][b] += xr[a] * wr[b];
        }
    }

    float bv[4];
    if (BIAS) {
#pragma unroll
        for (int b = 0; b < 4; b++) bv[b] = bias[col0 + cg * 4 + b];
    }
#pragma unroll
    for (int a = 0; a < 4; a++) {
        int gr = row0 + rg * 4 + a;
        if (gr >= nrows) continue;
        float d = SCALE ? dinv[gr] : 1.f;
        float o[4];
#pragma unroll
        for (int b = 0; b < 4; b++) {
            float v = acc[a][b];
            if (BIAS) v += bv[b];
            if (RELU) v = fmaxf(v, 0.f);
            o[b] = v * d;
        }
        *reinterpret_cast<float4*>(&out[(size_t)gr * NOUT + col0 + cg * 4]) =
            make_float4(o[0], o[1], o[2], o[3]);
    }
}

// ---------------- launch ----------------

extern "C" void kernel_launch(void* const* d_in, const int* in_sizes, int n_in,
                              void* d_out, int out_size, void* d_ws, size_t ws_size,
                              hipStream_t stream) {
    const float* feat = (const float*)d_in[0]; // [N, 64]
    const float* W1 = (const float*)d_in[1];   // [64, 128]
    const float* b1 = (const float*)d_in[2];
    const float* W2 = (const float*)d_in[3];   // [128, 128]
    const float* b2 = (const float*)d_in[4];
    const float* W3 = (const float*)d_in[5];   // [128, 64]
    const float* b3 = (const float*)d_in[6];
    const int* ei = (const int*)d_in[7];       // [2, E]
    const int* row = ei;
    const int* col = ei + N_EDGES;
    float* out = (float*)d_out;

    // workspace bump allocator (256B aligned)
    char* ws = (char*)d_ws;
    size_t off = 0;
    auto alloc = [&](size_t bytes) {
        void* p = ws + off;
        off = alignUp(off + bytes, 256);
        return p;
    };
    float* B0      = (float*)alloc((size_t)N_NODES * 128 * 4);
    float* B1      = (float*)alloc((size_t)N_NODES * 128 * 4);
    float* dinv    = (float*)alloc((size_t)N_NODES * 4);
    int*   count   = (int*)alloc((size_t)N_NODES * 4);
    int*   offsets = (int*)alloc((size_t)N_NODES * 4);
    int*   cursor  = (int*)alloc((size_t)N_NODES * 4);
    int*   bsum    = (int*)alloc(1024);
    int*   csr_col = (int*)alloc((size_t)(N_EDGES + 16) * 4); // +16 pad for over-read
    // featS (N x 64) overlays B1: dead before GEMM1 writes B1.
    float* featS   = B1;

    const int eb = (N_EDGES + 255) / 256;
    const int rb64 = (N_NODES + 63) / 64; // 782 row blocks
    const int agg_grid = N_NODES / 4;     // 12500 (one node per wave)

    // CSR build (every call — no cached state allowed)
    k_zero_i32<<<(N_NODES + 255) / 256, 256, 0, stream>>>(count, N_NODES);
    k_zero_i32<<<1, 256, 0, stream>>>(csr_col + N_EDGES, 16); // zero pad
    k_count<<<eb, 256, 0, stream>>>(row, count);
    k_blocksum<<<SCAN_BLOCKS, 256, 0, stream>>>(count, bsum);
    k_scan_bsum<<<1, 256, 0, stream>>>(bsum);
    k_scan_final<<<SCAN_BLOCKS, 256, 0, stream>>>(count, bsum, offsets, cursor, dinv);
    k_scatter<<<eb, 256, 0, stream>>>(row, col, cursor, csr_col);

    // features pre-scaled by dinv (so aggregate gathers need no dinv[c])
    k_prescale64<<<(N_NODES * 16 + 255) / 256, 256, 0, stream>>>(feat, dinv, featS);

    // Layer 1: agg1 = A_hat@feat (F=64), then x1' = dinv .* relu(agg1@W1+b1)
    k_agg64<false><<<agg_grid, 256, 0, stream>>>(featS, B0, csr_col, offsets, count, dinv, nullptr);
    k_gemm<64, 128, true, true, true><<<rb64 * 2, 256, 0, stream>>>(B0, W1, b1, dinv, B1, N_NODES);

    // Layer 2: agg2 = A_hat@x1 (F=128), then x2 = relu(agg2@W2+b2) (unscaled)
    k_agg128<false><<<agg_grid, 256, 0, stream>>>(B1, B0, csr_col, offsets, count, dinv, nullptr);
    k_gemm<128, 128, true, true, false><<<rb64 * 2, 256, 0, stream>>>(B0, W2, b2, dinv, B1, N_NODES);

    // Layer 3: h3' = dinv .* (x2@W3), then out = A_hat-agg + b3
    k_gemm<128, 64, false, false, true><<<rb64, 256, 0, stream>>>(B1, W3, nullptr, dinv, B0, N_NODES);
    k_agg64<true><<<agg_grid, 256, 0, stream>>>(B0, out, csr_col, offsets, count, dinv, b3);
}

// Round 4
// 316.366 us; speedup vs baseline: 2.1033x; 2.1033x over previous
//
#include <hip/hip_runtime.h>

#define N_NODES 50000
#define N_EDGES 800000

#define SCAN_CHUNK 256
#define SCAN_BLOCKS ((N_NODES + SCAN_CHUNK - 1) / SCAN_CHUNK) // 196

static inline size_t alignUp(size_t x, size_t a) { return (x + a - 1) & ~(a - 1); }

// ---------------- CSR build ----------------

__global__ void k_zero_i32(int* __restrict__ p, int n) {
    int i = blockIdx.x * 256 + threadIdx.x;
    if (i < n) p[i] = 0;
}

__global__ void k_count(const int* __restrict__ row, int* __restrict__ count) {
    int e = blockIdx.x * 256 + threadIdx.x;
    if (e < N_EDGES) atomicAdd(&count[row[e]], 1);
}

__global__ void k_blocksum(const int* __restrict__ count, int* __restrict__ bsum) {
    __shared__ int s[256];
    int t = threadIdx.x;
    int i = blockIdx.x * 256 + t;
    int v = (i < N_NODES) ? count[i] : 0;
    s[t] = v;
    __syncthreads();
    for (int off = 128; off > 0; off >>= 1) {
        if (t < off) s[t] += s[t + off];
        __syncthreads();
    }
    if (t == 0) bsum[blockIdx.x] = s[0];
}

__global__ void k_scan_bsum(int* __restrict__ bsum) {
    __shared__ int s[256];
    int t = threadIdx.x;
    int v = (t < SCAN_BLOCKS) ? bsum[t] : 0;
    s[t] = v;
    __syncthreads();
    for (int off = 1; off < 256; off <<= 1) {
        int add = (t >= off) ? s[t - off] : 0;
        __syncthreads();
        s[t] += add;
        __syncthreads();
    }
    if (t < SCAN_BLOCKS) bsum[t] = s[t] - v; // exclusive
}

__global__ void k_scan_final(const int* __restrict__ count, const int* __restrict__ bsum,
                             int* __restrict__ offsets, int* __restrict__ cursor,
                             float* __restrict__ dinv) {
    __shared__ int s[256];
    int t = threadIdx.x;
    int i = blockIdx.x * 256 + t;
    int v = (i < N_NODES) ? count[i] : 0;
    s[t] = v;
    __syncthreads();
    for (int off = 1; off < 256; off <<= 1) {
        int add = (t >= off) ? s[t - off] : 0;
        __syncthreads();
        s[t] += add;
        __syncthreads();
    }
    if (i < N_NODES) {
        int excl = s[t] - v + bsum[blockIdx.x];
        offsets[i] = excl;
        cursor[i]  = excl;
        dinv[i]    = rsqrtf((float)(v + 1)); // +1 self-loop; always > 0
    }
}

__global__ void k_scatter(const int* __restrict__ row, const int* __restrict__ col,
                          int* __restrict__ cursor, int* __restrict__ csr_col) {
    int e = blockIdx.x * 256 + threadIdx.x;
    if (e < N_EDGES) {
        int r = row[e];
        int pos = atomicAdd(&cursor[r], 1);
        csr_col[pos] = col[e];
    }
}

// ---------------- prescale: o[i,:] = dinv[i] * f[i,:]  (F=64, float4 grain) ----

__global__ void k_prescale64(const float* __restrict__ f, const float* __restrict__ dinv,
                             float* __restrict__ o) {
    int i = blockIdx.x * 256 + threadIdx.x; // float4 index
    if (i < N_NODES * 16) {
        int node = i >> 4;
        float d = dinv[node];
        float4 v = reinterpret_cast<const float4*>(f)[i];
        reinterpret_cast<float4*>(o)[i] = make_float4(v.x * d, v.y * d, v.z * d, v.w * d);
    }
}

// ---------------- Aggregation over PRE-SCALED rows ----------------
// out[i] = dinv_i * ( h'[i] + sum_c h'[c] ) (+bias), h' = dinv .* h
// One node per WAVE (zero inter-node divergence). Predicated full-width
// batches; csr_col is padded by 16 zeroed entries so over-read is safe.

// F=128: 64 lanes x float2 = one row; 8 edges per batch.
template <bool BIAS>
__global__ __launch_bounds__(256) void k_agg128(const float* __restrict__ hs, float* __restrict__ out,
        const int* __restrict__ csr_col, const int* __restrict__ offsets,
        const int* __restrict__ count, const float* __restrict__ dinv,
        const float* __restrict__ bias) {
    int lane = threadIdx.x & 63;
    int node = blockIdx.x * 4 + (threadIdx.x >> 6);
    const float2* h2 = reinterpret_cast<const float2*>(hs);

    float ax[8], ay[8];
#pragma unroll
    for (int u = 0; u < 8; u++) { ax[u] = 0.f; ay[u] = 0.f; }

    int n = count[node];
    const int* cp = csr_col + offsets[node];

    int e = 0;
    for (; e + 8 <= n; e += 8) {
        int c[8];
#pragma unroll
        for (int u = 0; u < 8; u++) c[u] = cp[e + u];
#pragma unroll
        for (int u = 0; u < 8; u++) {
            float2 v = h2[(size_t)c[u] * 64 + lane];
            ax[u] += v.x; ay[u] += v.y;
        }
    }
    if (e < n) { // one predicated batch covers rem 1..7
        int c[8];
#pragma unroll
        for (int u = 0; u < 8; u++) c[u] = cp[e + u]; // padded, safe
#pragma unroll
        for (int u = 0; u < 8; u++) {
            float2 v = h2[(size_t)c[u] * 64 + lane];
            if (e + u < n) { ax[u] += v.x; ay[u] += v.y; }
        }
    }

    float sx = 0.f, sy = 0.f;
#pragma unroll
    for (int u = 0; u < 8; u++) { sx += ax[u]; sy += ay[u]; }
    float2 self = h2[(size_t)node * 64 + lane];
    float d = dinv[node];
    float ox = (sx + self.x) * d, oy = (sy + self.y) * d;
    if (BIAS) { ox += bias[2 * lane]; oy += bias[2 * lane + 1]; }
    reinterpret_cast<float2*>(out)[(size_t)node * 64 + lane] = make_float2(ox, oy);
}

// F=64: 32 lanes x float2 = one row; each load slot covers TWO edges
// (lane half 0 -> edge e+2u, half 1 -> edge e+2u+1): 16 edges per batch.
template <bool BIAS>
__global__ __launch_bounds__(256) void k_agg64(const float* __restrict__ hs, float* __restrict__ out,
        const int* __restrict__ csr_col, const int* __restrict__ offsets,
        const int* __restrict__ count, const float* __restrict__ dinv,
        const float* __restrict__ bias) {
    int lane = threadIdx.x & 63;
    int node = blockIdx.x * 4 + (threadIdx.x >> 6);
    int half = lane >> 5;
    int f2 = lane & 31;
    const float2* h2 = reinterpret_cast<const float2*>(hs);

    float ax[8], ay[8];
#pragma unroll
    for (int u = 0; u < 8; u++) { ax[u] = 0.f; ay[u] = 0.f; }

    int n = count[node];
    const int* cp = csr_col + offsets[node];

    int e = 0;
    for (; e + 16 <= n; e += 16) {
        int c[8];
#pragma unroll
        for (int u = 0; u < 8; u++) c[u] = cp[e + 2 * u + half];
#pragma unroll
        for (int u = 0; u < 8; u++) {
            float2 v = h2[(size_t)c[u] * 32 + f2];
            ax[u] += v.x; ay[u] += v.y;
        }
    }
    if (e < n) { // one predicated batch covers rem 1..15
#pragma unroll
        for (int u = 0; u < 8; u++) {
            int eid = e + 2 * u + half;
            int c = cp[eid]; // padded, safe
            float2 v = h2[(size_t)c * 32 + f2];
            if (eid < n) { ax[u] += v.x; ay[u] += v.y; }
        }
    }

    float sx = 0.f, sy = 0.f;
#pragma unroll
    for (int u = 0; u < 8; u++) { sx += ax[u]; sy += ay[u]; }
    sx += __shfl_xor(sx, 32);
    sy += __shfl_xor(sy, 32);
    if (half == 0) {
        float2 self = h2[(size_t)node * 32 + f2];
        float d = dinv[node];
        float ox = (sx + self.x) * d, oy = (sy + self.y) * d;
        if (BIAS) { ox += bias[2 * f2]; oy += bias[2 * f2 + 1]; }
        reinterpret_cast<float2*>(out)[(size_t)node * 32 + f2] = make_float2(ox, oy);
    }
}

// ---------------- fp32 GEMM (R2-proven structure + 64-col split) ----------------
// out[r,c] = post( x[r,:] @ W[:,c] ), post = (+bias) -> relu -> (*dinv[r])
// BK=32, BN=64, BM=128 (8x4 micro) or BM=64 (4x4 micro). 256 threads.
// xt transposed [k][r], XOR swizzle r^ (k&28): 2-way banks max (free, m136).
// __launch_bounds__(256,4) caps VGPR at 128 (R3 spilled at 256 VGPR);
// '#pragma unroll 1' on the K-tile loop prevents whole-kernel flattening.

template <int K, int NOUT, int BM, bool RELU, bool BIAS, bool SCALE>
__global__ __launch_bounds__(256, 4) void k_gemm(const float* __restrict__ x,
        const float* __restrict__ W, const float* __restrict__ bias,
        const float* __restrict__ dinv, float* __restrict__ out, int nrows) {
    constexpr int BK = 32, BN = 64;
    constexpr int NCB = NOUT / BN;  // column blocks per row
    constexpr int RPT = BM / 16;    // rows per thread (8 or 4)
    __shared__ float xt[BK * BM];
    __shared__ float wt[BK * BN];

    int tid = threadIdx.x;
    int rg = tid & 15;  // row group
    int cg = tid >> 4;  // col group: cols cg*4..+3 of the 64-col strip
    int row0 = (blockIdx.x / NCB) * BM;
    int col0 = (blockIdx.x % NCB) * BN;

    float acc[RPT][4] = {};

#pragma unroll 1
    for (int kk = 0; kk < K; kk += BK) {
        __syncthreads();
        // ---- x tile: BM rows x 32 k, coalesced float4, swizzled transpose store
#pragma unroll
        for (int t = 0; t < BM / 32; ++t) {
            int idx = tid + t * 256;
            int r = idx >> 3;
            int kc = (idx & 7) * 4;
            float4 v = make_float4(0.f, 0.f, 0.f, 0.f);
            int gr = row0 + r;
            if (gr < nrows) v = *reinterpret_cast<const float4*>(&x[(size_t)gr * K + kk + kc]);
            int rc = r ^ kc; // kc in {0..28}: swizzle within 32-row stripe
            xt[(kc + 0) * BM + rc] = v.x;
            xt[(kc + 1) * BM + rc] = v.y;
            xt[(kc + 2) * BM + rc] = v.z;
            xt[(kc + 3) * BM + rc] = v.w;
        }
        // ---- W tile: 32 k x 64 n
#pragma unroll
        for (int t = 0; t < 2; ++t) {
            int idx = tid + t * 256;
            int k = idx >> 4;
            int c = (idx & 15) * 4;
            *reinterpret_cast<float4*>(&wt[k * BN + c]) =
                *reinterpret_cast<const float4*>(&W[(size_t)(kk + k) * NOUT + col0 + c]);
        }
        __syncthreads();

#pragma unroll
        for (int k = 0; k < BK; ++k) {
            int s = k & 28;
            float4 wv = *reinterpret_cast<const float4*>(&wt[k * BN + cg * 4]);
            float wr[4] = {wv.x, wv.y, wv.z, wv.w};
            float xr[RPT];
            float4 x0 = *reinterpret_cast<const float4*>(&xt[k * BM + ((rg * 4) ^ s)]);
            xr[0] = x0.x; xr[1] = x0.y; xr[2] = x0.z; xr[3] = x0.w;
            if (RPT == 8) {
                float4 x1 = *reinterpret_cast<const float4*>(&xt[k * BM + (((rg * 4) ^ s) + 64)]);
                xr[4] = x1.x; xr[5] = x1.y; xr[6] = x1.z; xr[7] = x1.w;
            }
#pragma unroll
            for (int a = 0; a < RPT; a++)
#pragma unroll
                for (int b = 0; b < 4; b++) acc[a][b] += xr[a] * wr[b];
        }
    }

    float bv[4];
    if (BIAS) {
#pragma unroll
        for (int b = 0; b < 4; b++) bv[b] = bias[col0 + cg * 4 + b];
    }
#pragma unroll
    for (int a = 0; a < RPT; a++) {
        int r = rg * 4 + (a & 3) + ((a >= 4) ? 64 : 0);
        int gr = row0 + r;
        if (gr >= nrows) continue;
        float d = SCALE ? dinv[gr] : 1.f;
        float o[4];
#pragma unroll
        for (int b = 0; b < 4; b++) {
            float v = acc[a][b];
            if (BIAS) v += bv[b];
            if (RELU) v = fmaxf(v, 0.f);
            o[b] = v * d;
        }
        *reinterpret_cast<float4*>(&out[(size_t)gr * NOUT + col0 + cg * 4]) =
            make_float4(o[0], o[1], o[2], o[3]);
    }
}

// ---------------- launch ----------------

extern "C" void kernel_launch(void* const* d_in, const int* in_sizes, int n_in,
                              void* d_out, int out_size, void* d_ws, size_t ws_size,
                              hipStream_t stream) {
    const float* feat = (const float*)d_in[0]; // [N, 64]
    const float* W1 = (const float*)d_in[1];   // [64, 128]
    const float* b1 = (const float*)d_in[2];
    const float* W2 = (const float*)d_in[3];   // [128, 128]
    const float* b2 = (const float*)d_in[4];
    const float* W3 = (const float*)d_in[5];   // [128, 64]
    const float* b3 = (const float*)d_in[6];
    const int* ei = (const int*)d_in[7];       // [2, E]
    const int* row = ei;
    const int* col = ei + N_EDGES;
    float* out = (float*)d_out;

    // workspace bump allocator (256B aligned)
    char* ws = (char*)d_ws;
    size_t off = 0;
    auto alloc = [&](size_t bytes) {
        void* p = ws + off;
        off = alignUp(off + bytes, 256);
        return p;
    };
    float* B0      = (float*)alloc((size_t)N_NODES * 128 * 4);
    float* B1      = (float*)alloc((size_t)N_NODES * 128 * 4);
    float* dinv    = (float*)alloc((size_t)N_NODES * 4);
    int*   count   = (int*)alloc((size_t)N_NODES * 4);
    int*   offsets = (int*)alloc((size_t)N_NODES * 4);
    int*   cursor  = (int*)alloc((size_t)N_NODES * 4);
    int*   bsum    = (int*)alloc(1024);
    int*   csr_col = (int*)alloc((size_t)(N_EDGES + 16) * 4); // +16 pad for over-read
    // featS (N x 64) overlays B1: dead before GEMM1 writes B1.
    float* featS   = B1;

    const int eb = (N_EDGES + 255) / 256;
    const int rb128 = (N_NODES + 127) / 128; // 391
    const int rb64  = (N_NODES + 63) / 64;   // 782
    const int agg_grid = N_NODES / 4;        // 12500 (one node per wave)

    // CSR build (every call — no cached state allowed)
    k_zero_i32<<<(N_NODES + 255) / 256, 256, 0, stream>>>(count, N_NODES);
    k_zero_i32<<<1, 256, 0, stream>>>(csr_col + N_EDGES, 16); // zero pad
    k_count<<<eb, 256, 0, stream>>>(row, count);
    k_blocksum<<<SCAN_BLOCKS, 256, 0, stream>>>(count, bsum);
    k_scan_bsum<<<1, 256, 0, stream>>>(bsum);
    k_scan_final<<<SCAN_BLOCKS, 256, 0, stream>>>(count, bsum, offsets, cursor, dinv);
    k_scatter<<<eb, 256, 0, stream>>>(row, col, cursor, csr_col);

    // features pre-scaled by dinv (so aggregate gathers need no dinv[c])
    k_prescale64<<<(N_NODES * 16 + 255) / 256, 256, 0, stream>>>(feat, dinv, featS);

    // Layer 1: agg1 = A_hat@feat (F=64), then x1' = dinv .* relu(agg1@W1+b1)
    k_agg64<false><<<agg_grid, 256, 0, stream>>>(featS, B0, csr_col, offsets, count, dinv, nullptr);
    k_gemm<64, 128, 128, true, true, true><<<rb128 * 2, 256, 0, stream>>>(B0, W1, b1, dinv, B1, N_NODES);

    // Layer 2: agg2 = A_hat@x1 (F=128), then x2 = relu(agg2@W2+b2) (unscaled)
    k_agg128<false><<<agg_grid, 256, 0, stream>>>(B1, B0, csr_col, offsets, count, dinv, nullptr);
    k_gemm<128, 128, 128, true, true, false><<<rb128 * 2, 256, 0, stream>>>(B0, W2, b2, dinv, B1, N_NODES);

    // Layer 3: h3' = dinv .* (x2@W3), then out = A_hat-agg + b3
    k_gemm<128, 64, 64, false, false, true><<<rb64, 256, 0, stream>>>(B1, W3, nullptr, dinv, B0, N_NODES);
    k_agg64<true><<<agg_grid, 256, 0, stream>>>(B0, out, csr_col, offsets, count, dinv, b3);
}

// Round 5
// 308.182 us; speedup vs baseline: 2.1592x; 1.0266x over previous
//
#include <hip/hip_runtime.h>

#define N_NODES 50000
#define N_EDGES 800000

#define SCAN_CHUNK 256
#define SCAN_BLOCKS ((N_NODES + SCAN_CHUNK - 1) / SCAN_CHUNK) // 196

static inline size_t alignUp(size_t x, size_t a) { return (x + a - 1) & ~(a - 1); }

// ---------------- CSR build ----------------

__global__ void k_zero_i32(int* __restrict__ p, int n) {
    int i = blockIdx.x * 256 + threadIdx.x;
    if (i < n) p[i] = 0;
}

// count degrees; first 32 threads also zero the csr_col over-read pad
__global__ void k_count(const int* __restrict__ row, int* __restrict__ count,
                        int* __restrict__ pad) {
    int e = blockIdx.x * 256 + threadIdx.x;
    if (e < 32) pad[e] = 0;
    if (e < N_EDGES) atomicAdd(&count[row[e]], 1);
}

__global__ void k_blocksum(const int* __restrict__ count, int* __restrict__ bsum) {
    __shared__ int s[256];
    int t = threadIdx.x;
    int i = blockIdx.x * 256 + t;
    int v = (i < N_NODES) ? count[i] : 0;
    s[t] = v;
    __syncthreads();
    for (int off = 128; off > 0; off >>= 1) {
        if (t < off) s[t] += s[t + off];
        __syncthreads();
    }
    if (t == 0) bsum[blockIdx.x] = s[0];
}

__global__ void k_scan_bsum(int* __restrict__ bsum) {
    __shared__ int s[256];
    int t = threadIdx.x;
    int v = (t < SCAN_BLOCKS) ? bsum[t] : 0;
    s[t] = v;
    __syncthreads();
    for (int off = 1; off < 256; off <<= 1) {
        int add = (t >= off) ? s[t - off] : 0;
        __syncthreads();
        s[t] += add;
        __syncthreads();
    }
    if (t < SCAN_BLOCKS) bsum[t] = s[t] - v; // exclusive
}

__global__ void k_scan_final(const int* __restrict__ count, const int* __restrict__ bsum,
                             int* __restrict__ offsets, int* __restrict__ cursor,
                             float* __restrict__ dinv) {
    __shared__ int s[256];
    int t = threadIdx.x;
    int i = blockIdx.x * 256 + t;
    int v = (i < N_NODES) ? count[i] : 0;
    s[t] = v;
    __syncthreads();
    for (int off = 1; off < 256; off <<= 1) {
        int add = (t >= off) ? s[t - off] : 0;
        __syncthreads();
        s[t] += add;
        __syncthreads();
    }
    if (i < N_NODES) {
        int excl = s[t] - v + bsum[blockIdx.x];
        offsets[i] = excl;
        cursor[i]  = excl;
        dinv[i]    = rsqrtf((float)(v + 1)); // +1 self-loop; always > 0
    }
}

__global__ void k_scatter(const int* __restrict__ row, const int* __restrict__ col,
                          int* __restrict__ cursor, int* __restrict__ csr_col) {
    int e = blockIdx.x * 256 + threadIdx.x;
    if (e < N_EDGES) {
        int r = row[e];
        int pos = atomicAdd(&cursor[r], 1);
        csr_col[pos] = col[e];
    }
}

// ---------------- prescale: o[i,:] = dinv[i] * f[i,:]  (F=64, float4 grain) ----

__global__ void k_prescale64(const float* __restrict__ f, const float* __restrict__ dinv,
                             float* __restrict__ o) {
    int i = blockIdx.x * 256 + threadIdx.x; // float4 index
    if (i < N_NODES * 16) {
        int node = i >> 4;
        float d = dinv[node];
        float4 v = reinterpret_cast<const float4*>(f)[i];
        reinterpret_cast<float4*>(o)[i] = make_float4(v.x * d, v.y * d, v.z * d, v.w * d);
    }
}

// ---------------- Aggregation over PRE-SCALED rows ----------------
// out[i] = dinv_i * ( h'[i] + sum_c h'[c] ) (+bias), h' = dinv .* h
// One node per WAVE. float4-grain gathers (1 KB per load instruction):
// F=128: 32 lanes cover a row, 2 edges per load slot -> 16 edges/batch.
// F=64 : 16 lanes cover a row, 4 edges per load slot -> 32 edges/batch.
// Tail batches always ISSUE all 8 loads (csr pad makes over-read safe,
// c=0 -> row 0, L1-hot) and predicate only the accumulate -> full MLP.

template <bool BIAS>
__global__ __launch_bounds__(256) void k_agg128(const float* __restrict__ hs, float* __restrict__ out,
        const int* __restrict__ csr_col, const int* __restrict__ offsets,
        const int* __restrict__ count, const float* __restrict__ dinv,
        const float* __restrict__ bias) {
    int lane = threadIdx.x & 63;
    int node = blockIdx.x * 4 + (threadIdx.x >> 6);
    int q = lane >> 5;        // edge parity within slot
    int f4 = lane & 31;       // float4 index within 128-float row
    const char* base = (const char*)hs;
    uint32_t fo = (uint32_t)f4 << 4;

    int n = __builtin_amdgcn_readfirstlane(count[node]);
    int start = __builtin_amdgcn_readfirstlane(offsets[node]);
    const int* cp = csr_col + start;

    float4 a0 = make_float4(0.f, 0.f, 0.f, 0.f);
    float4 a1 = make_float4(0.f, 0.f, 0.f, 0.f);

    int e = 0;
    for (; e + 16 <= n; e += 16) {
        int c[8];
#pragma unroll
        for (int u = 0; u < 8; u++) c[u] = cp[e + 2 * u + q];
        float4 v[8];
#pragma unroll
        for (int u = 0; u < 8; u++)
            v[u] = *reinterpret_cast<const float4*>(base + (((uint32_t)c[u] << 9) + fo));
#pragma unroll
        for (int u = 0; u < 8; u += 2) {
            a0.x += v[u].x; a0.y += v[u].y; a0.z += v[u].z; a0.w += v[u].w;
            a1.x += v[u+1].x; a1.y += v[u+1].y; a1.z += v[u+1].z; a1.w += v[u+1].w;
        }
    }
    if (e < n) {
        int c[8];
#pragma unroll
        for (int u = 0; u < 8; u++) c[u] = cp[e + 2 * u + q]; // padded, safe
        float4 v[8];
#pragma unroll
        for (int u = 0; u < 8; u++)
            v[u] = *reinterpret_cast<const float4*>(base + (((uint32_t)c[u] << 9) + fo));
#pragma unroll
        for (int u = 0; u < 8; u++) {
            if (e + 2 * u + q < n) {
                a0.x += v[u].x; a0.y += v[u].y; a0.z += v[u].z; a0.w += v[u].w;
            }
        }
    }

    float sx = a0.x + a1.x, sy = a0.y + a1.y, sz = a0.z + a1.z, sw = a0.w + a1.w;
    sx += __shfl_xor(sx, 32);
    sy += __shfl_xor(sy, 32);
    sz += __shfl_xor(sz, 32);
    sw += __shfl_xor(sw, 32);
    if (q == 0) {
        float4 self = *reinterpret_cast<const float4*>(base + ((uint32_t)node << 9) + fo);
        float d = dinv[node];
        float ox = (sx + self.x) * d, oy = (sy + self.y) * d;
        float oz = (sz + self.z) * d, ow = (sw + self.w) * d;
        if (BIAS) {
            float4 bv = *reinterpret_cast<const float4*>(&bias[f4 * 4]);
            ox += bv.x; oy += bv.y; oz += bv.z; ow += bv.w;
        }
        *reinterpret_cast<float4*>((char*)out + ((uint32_t)node << 9) + fo) =
            make_float4(ox, oy, oz, ow);
    }
}

template <bool BIAS>
__global__ __launch_bounds__(256) void k_agg64(const float* __restrict__ hs, float* __restrict__ out,
        const int* __restrict__ csr_col, const int* __restrict__ offsets,
        const int* __restrict__ count, const float* __restrict__ dinv,
        const float* __restrict__ bias) {
    int lane = threadIdx.x & 63;
    int node = blockIdx.x * 4 + (threadIdx.x >> 6);
    int q = lane >> 4;        // edge sub-slot (0..3)
    int f4 = lane & 15;       // float4 index within 64-float row
    const char* base = (const char*)hs;
    uint32_t fo = (uint32_t)f4 << 4;

    int n = __builtin_amdgcn_readfirstlane(count[node]);
    int start = __builtin_amdgcn_readfirstlane(offsets[node]);
    const int* cp = csr_col + start;

    float4 a0 = make_float4(0.f, 0.f, 0.f, 0.f);
    float4 a1 = make_float4(0.f, 0.f, 0.f, 0.f);

    int e = 0;
    for (; e + 32 <= n; e += 32) {
        int c[8];
#pragma unroll
        for (int u = 0; u < 8; u++) c[u] = cp[e + 4 * u + q];
        float4 v[8];
#pragma unroll
        for (int u = 0; u < 8; u++)
            v[u] = *reinterpret_cast<const float4*>(base + (((uint32_t)c[u] << 8) + fo));
#pragma unroll
        for (int u = 0; u < 8; u += 2) {
            a0.x += v[u].x; a0.y += v[u].y; a0.z += v[u].z; a0.w += v[u].w;
            a1.x += v[u+1].x; a1.y += v[u+1].y; a1.z += v[u+1].z; a1.w += v[u+1].w;
        }
    }
    if (e < n) {
        int c[8];
#pragma unroll
        for (int u = 0; u < 8; u++) c[u] = cp[e + 4 * u + q]; // padded, safe
        float4 v[8];
#pragma unroll
        for (int u = 0; u < 8; u++)
            v[u] = *reinterpret_cast<const float4*>(base + (((uint32_t)c[u] << 8) + fo));
#pragma unroll
        for (int u = 0; u < 8; u++) {
            if (e + 4 * u + q < n) {
                a0.x += v[u].x; a0.y += v[u].y; a0.z += v[u].z; a0.w += v[u].w;
            }
        }
    }

    float sx = a0.x + a1.x, sy = a0.y + a1.y, sz = a0.z + a1.z, sw = a0.w + a1.w;
    sx += __shfl_xor(sx, 16); sy += __shfl_xor(sy, 16);
    sz += __shfl_xor(sz, 16); sw += __shfl_xor(sw, 16);
    sx += __shfl_xor(sx, 32); sy += __shfl_xor(sy, 32);
    sz += __shfl_xor(sz, 32); sw += __shfl_xor(sw, 32);
    if (q == 0) {
        float4 self = *reinterpret_cast<const float4*>(base + ((uint32_t)node << 8) + fo);
        float d = dinv[node];
        float ox = (sx + self.x) * d, oy = (sy + self.y) * d;
        float oz = (sz + self.z) * d, ow = (sw + self.w) * d;
        if (BIAS) {
            float4 bv = *reinterpret_cast<const float4*>(&bias[f4 * 4]);
            ox += bv.x; oy += bv.y; oz += bv.z; ow += bv.w;
        }
        *reinterpret_cast<float4*>((char*)out + ((uint32_t)node << 8) + fo) =
            make_float4(ox, oy, oz, ow);
    }
}

// ---------------- fp32 GEMM (R4 known-good: BK=32, BN=64) ----------------
// out[r,c] = post( x[r,:] @ W[:,c] ), post = (+bias) -> relu -> (*dinv[r])
// __launch_bounds__(256,4) caps VGPR at 128 (R3 spilled at 256 VGPR);
// '#pragma unroll 1' on the K-tile loop prevents whole-kernel flattening.

template <int K, int NOUT, int BM, bool RELU, bool BIAS, bool SCALE>
__global__ __launch_bounds__(256, 4) void k_gemm(const float* __restrict__ x,
        const float* __restrict__ W, const float* __restrict__ bias,
        const float* __restrict__ dinv, float* __restrict__ out, int nrows) {
    constexpr int BK = 32, BN = 64;
    constexpr int NCB = NOUT / BN;  // column blocks per row
    constexpr int RPT = BM / 16;    // rows per thread (8 or 4)
    __shared__ float xt[BK * BM];
    __shared__ float wt[BK * BN];

    int tid = threadIdx.x;
    int rg = tid & 15;  // row group
    int cg = tid >> 4;  // col group: cols cg*4..+3 of the 64-col strip
    int row0 = (blockIdx.x / NCB) * BM;
    int col0 = (blockIdx.x % NCB) * BN;

    float acc[RPT][4] = {};

#pragma unroll 1
    for (int kk = 0; kk < K; kk += BK) {
        __syncthreads();
        // ---- x tile: BM rows x 32 k, coalesced float4, swizzled transpose store
#pragma unroll
        for (int t = 0; t < BM / 32; ++t) {
            int idx = tid + t * 256;
            int r = idx >> 3;
            int kc = (idx & 7) * 4;
            float4 v = make_float4(0.f, 0.f, 0.f, 0.f);
            int gr = row0 + r;
            if (gr < nrows) v = *reinterpret_cast<const float4*>(&x[(size_t)gr * K + kk + kc]);
            int rc = r ^ kc; // kc in {0..28}: swizzle within 32-row stripe
            xt[(kc + 0) * BM + rc] = v.x;
            xt[(kc + 1) * BM + rc] = v.y;
            xt[(kc + 2) * BM + rc] = v.z;
            xt[(kc + 3) * BM + rc] = v.w;
        }
        // ---- W tile: 32 k x 64 n
#pragma unroll
        for (int t = 0; t < 2; ++t) {
            int idx = tid + t * 256;
            int k = idx >> 4;
            int c = (idx & 15) * 4;
            *reinterpret_cast<float4*>(&wt[k * BN + c]) =
                *reinterpret_cast<const float4*>(&W[(size_t)(kk + k) * NOUT + col0 + c]);
        }
        __syncthreads();

#pragma unroll
        for (int k = 0; k < BK; ++k) {
            int s = k & 28;
            float4 wv = *reinterpret_cast<const float4*>(&wt[k * BN + cg * 4]);
            float wr[4] = {wv.x, wv.y, wv.z, wv.w};
            float xr[RPT];
            float4 x0 = *reinterpret_cast<const float4*>(&xt[k * BM + ((rg * 4) ^ s)]);
            xr[0] = x0.x; xr[1] = x0.y; xr[2] = x0.z; xr[3] = x0.w;
            if (RPT == 8) {
                float4 x1 = *reinterpret_cast<const float4*>(&xt[k * BM + (((rg * 4) ^ s) + 64)]);
                xr[4] = x1.x; xr[5] = x1.y; xr[6] = x1.z; xr[7] = x1.w;
            }
#pragma unroll
            for (int a = 0; a < RPT; a++)
#pragma unroll
                for (int b = 0; b < 4; b++) acc[a][b] += xr[a] * wr[b];
        }
    }

    float bv[4];
    if (BIAS) {
#pragma unroll
        for (int b = 0; b < 4; b++) bv[b] = bias[col0 + cg * 4 + b];
    }
#pragma unroll
    for (int a = 0; a < RPT; a++) {
        int r = rg * 4 + (a & 3) + ((a >= 4) ? 64 : 0);
        int gr = row0 + r;
        if (gr >= nrows) continue;
        float d = SCALE ? dinv[gr] : 1.f;
        float o[4];
#pragma unroll
        for (int b = 0; b < 4; b++) {
            float v = acc[a][b];
            if (BIAS) v += bv[b];
            if (RELU) v = fmaxf(v, 0.f);
            o[b] = v * d;
        }
        *reinterpret_cast<float4*>(&out[(size_t)gr * NOUT + col0 + cg * 4]) =
            make_float4(o[0], o[1], o[2], o[3]);
    }
}

// ---------------- launch ----------------

extern "C" void kernel_launch(void* const* d_in, const int* in_sizes, int n_in,
                              void* d_out, int out_size, void* d_ws, size_t ws_size,
                              hipStream_t stream) {
    const float* feat = (const float*)d_in[0]; // [N, 64]
    const float* W1 = (const float*)d_in[1];   // [64, 128]
    const float* b1 = (const float*)d_in[2];
    const float* W2 = (const float*)d_in[3];   // [128, 128]
    const float* b2 = (const float*)d_in[4];
    const float* W3 = (const float*)d_in[5];   // [128, 64]
    const float* b3 = (const float*)d_in[6];
    const int* ei = (const int*)d_in[7];       // [2, E]
    const int* row = ei;
    const int* col = ei + N_EDGES;
    float* out = (float*)d_out;

    // workspace bump allocator (256B aligned)
    char* ws = (char*)d_ws;
    size_t off = 0;
    auto alloc = [&](size_t bytes) {
        void* p = ws + off;
        off = alignUp(off + bytes, 256);
        return p;
    };
    float* B0      = (float*)alloc((size_t)N_NODES * 128 * 4);
    float* B1      = (float*)alloc((size_t)N_NODES * 128 * 4);
    float* dinv    = (float*)alloc((size_t)N_NODES * 4);
    int*   count   = (int*)alloc((size_t)N_NODES * 4);
    int*   offsets = (int*)alloc((size_t)N_NODES * 4);
    int*   cursor  = (int*)alloc((size_t)N_NODES * 4);
    int*   bsum    = (int*)alloc(1024);
    int*   csr_col = (int*)alloc((size_t)(N_EDGES + 32) * 4); // +32 pad for over-read
    // featS (N x 64) overlays B1: dead before GEMM1 writes B1.
    float* featS   = B1;

    const int eb = (N_EDGES + 255) / 256;
    const int rb128 = (N_NODES + 127) / 128; // 391
    const int rb64  = (N_NODES + 63) / 64;   // 782
    const int agg_grid = N_NODES / 4;        // 12500 (one node per wave)

    // CSR build (every call — no cached state allowed)
    k_zero_i32<<<(N_NODES + 255) / 256, 256, 0, stream>>>(count, N_NODES);
    k_count<<<eb, 256, 0, stream>>>(row, count, csr_col + N_EDGES);
    k_blocksum<<<SCAN_BLOCKS, 256, 0, stream>>>(count, bsum);
    k_scan_bsum<<<1, 256, 0, stream>>>(bsum);
    k_scan_final<<<SCAN_BLOCKS, 256, 0, stream>>>(count, bsum, offsets, cursor, dinv);
    k_scatter<<<eb, 256, 0, stream>>>(row, col, cursor, csr_col);

    // features pre-scaled by dinv (so aggregate gathers need no dinv[c])
    k_prescale64<<<(N_NODES * 16 + 255) / 256, 256, 0, stream>>>(feat, dinv, featS);

    // Layer 1: agg1 = A_hat@feat (F=64), then x1' = dinv .* relu(agg1@W1+b1)
    k_agg64<false><<<agg_grid, 256, 0, stream>>>(featS, B0, csr_col, offsets, count, dinv, nullptr);
    k_gemm<64, 128, 128, true, true, true><<<rb128 * 2, 256, 0, stream>>>(B0, W1, b1, dinv, B1, N_NODES);

    // Layer 2: agg2 = A_hat@x1 (F=128), then x2 = relu(agg2@W2+b2) (unscaled)
    k_agg128<false><<<agg_grid, 256, 0, stream>>>(B1, B0, csr_col, offsets, count, dinv, nullptr);
    k_gemm<128, 128, 128, true, true, false><<<rb128 * 2, 256, 0, stream>>>(B0, W2, b2, dinv, B1, N_NODES);

    // Layer 3: h3' = dinv .* (x2@W3), then out = A_hat-agg + b3
    k_gemm<128, 64, 64, false, false, true><<<rb64, 256, 0, stream>>>(B1, W3, nullptr, dinv, B0, N_NODES);
    k_agg64<true><<<agg_grid, 256, 0, stream>>>(B0, out, csr_col, offsets, count, dinv, b3);
}